// Round 2
// baseline (43.172 us; speedup 1.0000x reference)
//
#include <hip/hip_runtime.h>
#include <math.h>

#define BATCH 16
#define NPTS 17
#define MPTS 4096
#define NPAIR 136                    // 17*16/2 pairs (i>j)
#define NPAIRS_TOTAL (BATCH * NPAIR) // 2176
#define NBLK (NPAIRS_TOTAL / 4)      // 544 blocks, 4 waves/block, 1 wave per pair
#define CNT 5
#define MAXDIS 1e-3f
#define EPS_ABS 1e-5f

union F2U64 {
    float2 f;
    unsigned long long u;
};

// One wave per (batch, pair): 64 lanes stripe the 4096 gt points (float4 = 2
// points/lane/iter, 32 iters), keep 5 running mins, butterfly-reduce in-wave.
// Lane 0 release-stores the packed (cos, cnt) slot. Last block to finish
// (agent-scope ticket) reduces all 2176 slots and writes the scalar.
__global__ __launch_bounds__(256) void fused_kernel(const float* __restrict__ recon,
                                                    const float* __restrict__ gt,
                                                    unsigned long long* __restrict__ slots,
                                                    unsigned int* __restrict__ ticket,
                                                    float* __restrict__ out) {
    const int wv = blockIdx.x * 4 + (threadIdx.x >> 6); // pair id in [0, 2176)
    const int lane = threadIdx.x & 63;
    const int b = wv / NPAIR;
    const int p = wv - b * NPAIR;
    // decode p -> (i, j), p = i*(i-1)/2 + j, j < i  (wave-uniform loop)
    int i = 1;
    while ((i * (i + 1)) / 2 <= p) ++i;
    const int j = p - (i * (i - 1)) / 2;

    const float* rp = recon + b * NPTS * 2;
    const float pix = rp[2 * i], piy = rp[2 * i + 1];
    const float pjx = rp[2 * j], pjy = rp[2 * j + 1];

    // K_c = p_i * t + p_j * (1-t), t = {0,.25,.5,.75,1}
    float m2Kx[CNT], m2Ky[CNT], k2[CNT], mn[CNT];
    #pragma unroll
    for (int c = 0; c < CNT; ++c) {
        const float t = 0.25f * (float)c;
        const float omt = 1.0f - t;
        const float Kx = pix * t + pjx * omt;
        const float Ky = piy * t + pjy * omt;
        k2[c] = Kx * Kx + Ky * Ky;
        m2Kx[c] = -2.0f * Kx;
        m2Ky[c] = -2.0f * Ky;
        mn[c] = 1e30f;
    }

    const float4* g4 = (const float4*)(gt + (size_t)b * MPTS * 2);
    #pragma unroll 4
    for (int q = lane; q < MPTS / 2; q += 64) {
        const float4 g = g4[q];
        const float g2a = g.x * g.x + g.y * g.y;
        const float g2b = g.z * g.z + g.w * g.w;
        #pragma unroll
        for (int c = 0; c < CNT; ++c) {
            // d2 = (k2 + g2) - 2*(Kx*gx + Ky*gy), fused form
            const float da = fmaf(m2Kx[c], g.x, fmaf(m2Ky[c], g.y, k2[c] + g2a));
            const float db = fmaf(m2Kx[c], g.z, fmaf(m2Ky[c], g.w, k2[c] + g2b));
            mn[c] = fminf(mn[c], fminf(da, db));
        }
    }

    // in-wave butterfly min reduce
    #pragma unroll
    for (int c = 0; c < CNT; ++c) {
        #pragma unroll
        for (int off = 32; off > 0; off >>= 1)
            mn[c] = fminf(mn[c], __shfl_xor(mn[c], off, 64));
    }

    if (lane == 0) {
        const float cdis = ((((mn[0] + mn[1]) + mn[2]) + mn[3]) + mn[4]) / 5.0f;
        float cosv = 0.0f, cntv = 0.0f;
        if (cdis < MAXDIS) {
            const float u0x = rp[0], u0y = rp[1];
            const float uix = u0x - pix, uiy = u0y - piy;
            const float ujx = u0x - pjx, ujy = u0y - pjy;
            const float dot = fabsf(uix * ujx + uiy * ujy);
            const float ai = sqrtf((uix * uix + EPS_ABS) + (uiy * uiy + EPS_ABS));
            const float aj = sqrtf((ujx * ujx + EPS_ABS) + (ujy * ujy + EPS_ABS));
            cosv = dot / (ai * aj);
            cntv = 1.0f;
        }
        F2U64 u;
        u.f.x = cosv;
        u.f.y = cntv;
        __hip_atomic_store(&slots[wv], u.u, __ATOMIC_RELEASE, __HIP_MEMORY_SCOPE_AGENT);
    }

    __syncthreads();
    __shared__ int isLast;
    if (threadIdx.x == 0) {
        const unsigned int old =
            __hip_atomic_fetch_add(ticket, 1u, __ATOMIC_ACQ_REL, __HIP_MEMORY_SCOPE_AGENT);
        isLast = (old == NBLK - 1) ? 1 : 0;
    }
    __syncthreads();
    if (!isLast) return;

    // last block: deterministic fixed-order reduction of all 2176 slots
    __threadfence(); // agent-scope acquire for all threads in this block
    __shared__ float scos[256];
    __shared__ float scnt[256];
    float c = 0.0f, n = 0.0f;
    for (int k = threadIdx.x; k < NPAIRS_TOTAL; k += 256) {
        F2U64 w;
        w.u = __hip_atomic_load(&slots[k], __ATOMIC_RELAXED, __HIP_MEMORY_SCOPE_AGENT);
        c += w.f.x;
        n += w.f.y;
    }
    scos[threadIdx.x] = c;
    scnt[threadIdx.x] = n;
    __syncthreads();
    for (int s = 128; s > 0; s >>= 1) {
        if (threadIdx.x < (unsigned)s) {
            scos[threadIdx.x] += scos[threadIdx.x + s];
            scnt[threadIdx.x] += scnt[threadIdx.x + s];
        }
        __syncthreads();
    }
    if (threadIdx.x == 0) out[0] = scos[0] / (1.0f + scnt[0]);
}

extern "C" void kernel_launch(void* const* d_in, const int* in_sizes, int n_in,
                              void* d_out, int out_size, void* d_ws, size_t ws_size,
                              hipStream_t stream) {
    const float* recon = (const float*)d_in[0]; // [16,17,2] f32
    const float* gt = (const float*)d_in[1];    // [16,4096,2] f32
    float* out = (float*)d_out;                 // scalar f32

    unsigned long long* slots = (unsigned long long*)d_ws;
    unsigned int* ticket = (unsigned int*)((char*)d_ws + (size_t)NPAIRS_TOTAL * 8);

    // re-init the ticket every call (ws is poisoned once, never re-poisoned)
    hipMemsetAsync(ticket, 0, sizeof(unsigned int), stream);
    fused_kernel<<<NBLK, 256, 0, stream>>>(recon, gt, slots, ticket, out);
}

// Round 4
// 36.735 us; speedup vs baseline: 1.1752x; 1.1752x over previous
//
#include <hip/hip_runtime.h>
#include <math.h>

#define BATCH 16
#define NPTS 17
#define MPTS 4096
#define NPAIR 136                    // 17*16/2 pairs (i>j)
#define NPAIRS_TOTAL (BATCH * NPAIR) // 2176
#define NBLK (NPAIRS_TOTAL / 4)      // 544 blocks, 4 waves/block, 1 wave per pair
#define CNT 5
#define MAXDIS 1e-3f
#define EPS_ABS 1e-5f

union F2U64 {
    float2 f;
    unsigned long long u;
};

// Single kernel, single graph node. One wave per (batch, pair): 64 lanes
// stripe the 4096 gt points, keep 5 running mins, butterfly-reduce in-wave,
// lane 0 release-stores the packed (cos, cnt) slot. Last block to finish
// reduces all slots. The "last" test is (old % NBLK == NBLK-1), which selects
// exactly one of the 544 arrivals per call REGARDLESS of the ticket's
// starting value -- so no init/memset node is needed and every call does
// identical work with identical output.
__global__ __launch_bounds__(256) void fused_kernel(const float* __restrict__ recon,
                                                    const float* __restrict__ gt,
                                                    unsigned long long* __restrict__ slots,
                                                    unsigned int* __restrict__ ticket,
                                                    float* __restrict__ out) {
    const int wv = blockIdx.x * 4 + (threadIdx.x >> 6); // pair id in [0, 2176)
    const int lane = threadIdx.x & 63;
    const int b = wv / NPAIR;
    const int p = wv - b * NPAIR;
    // decode p -> (i, j), p = i*(i-1)/2 + j, j < i  (wave-uniform loop)
    int i = 1;
    while ((i * (i + 1)) / 2 <= p) ++i;
    const int j = p - (i * (i - 1)) / 2;

    const float* rp = recon + b * NPTS * 2;
    const float pix = rp[2 * i], piy = rp[2 * i + 1];
    const float pjx = rp[2 * j], pjy = rp[2 * j + 1];

    // K_c = p_i * t + p_j * (1-t), t = {0,.25,.5,.75,1}
    float m2Kx[CNT], m2Ky[CNT], k2[CNT], mn[CNT];
    #pragma unroll
    for (int c = 0; c < CNT; ++c) {
        const float t = 0.25f * (float)c;
        const float omt = 1.0f - t;
        const float Kx = pix * t + pjx * omt;
        const float Ky = piy * t + pjy * omt;
        k2[c] = Kx * Kx + Ky * Ky;
        m2Kx[c] = -2.0f * Kx;
        m2Ky[c] = -2.0f * Ky;
        mn[c] = 1e30f;
    }

    const float4* g4 = (const float4*)(gt + (size_t)b * MPTS * 2);
    #pragma unroll 4
    for (int q = lane; q < MPTS / 2; q += 64) {
        const float4 g = g4[q];
        const float g2a = g.x * g.x + g.y * g.y;
        const float g2b = g.z * g.z + g.w * g.w;
        #pragma unroll
        for (int c = 0; c < CNT; ++c) {
            // d2 = (k2 + g2) - 2*(Kx*gx + Ky*gy), fused
            const float da = fmaf(m2Kx[c], g.x, fmaf(m2Ky[c], g.y, k2[c] + g2a));
            const float db = fmaf(m2Kx[c], g.z, fmaf(m2Ky[c], g.w, k2[c] + g2b));
            mn[c] = fminf(mn[c], fminf(da, db));
        }
    }

    // in-wave butterfly min reduce
    #pragma unroll
    for (int c = 0; c < CNT; ++c) {
        #pragma unroll
        for (int off = 32; off > 0; off >>= 1)
            mn[c] = fminf(mn[c], __shfl_xor(mn[c], off, 64));
    }

    if (lane == 0) {
        const float cdis = ((((mn[0] + mn[1]) + mn[2]) + mn[3]) + mn[4]) / 5.0f;
        float cosv = 0.0f, cntv = 0.0f;
        if (cdis < MAXDIS) {
            const float u0x = rp[0], u0y = rp[1];
            const float uix = u0x - pix, uiy = u0y - piy;
            const float ujx = u0x - pjx, ujy = u0y - pjy;
            const float dot = fabsf(uix * ujx + uiy * ujy);
            const float ai = sqrtf((uix * uix + EPS_ABS) + (uiy * uiy + EPS_ABS));
            const float aj = sqrtf((ujx * ujx + EPS_ABS) + (ujy * ujy + EPS_ABS));
            cosv = dot / (ai * aj);
            cntv = 1.0f;
        }
        F2U64 u;
        u.f.x = cosv;
        u.f.y = cntv;
        __hip_atomic_store(&slots[wv], u.u, __ATOMIC_RELEASE, __HIP_MEMORY_SCOPE_AGENT);
    }

    __syncthreads();
    __shared__ int isLast;
    if (threadIdx.x == 0) {
        const unsigned int old =
            __hip_atomic_fetch_add(ticket, 1u, __ATOMIC_ACQ_REL, __HIP_MEMORY_SCOPE_AGENT);
        isLast = ((old % NBLK) == (NBLK - 1)) ? 1 : 0;
    }
    __syncthreads();
    if (!isLast) return;

    // last-arriving block: deterministic fixed-order reduction of all slots
    __threadfence(); // agent-scope acquire for the whole block
    __shared__ float scos[256];
    __shared__ float scnt[256];
    float c = 0.0f, n = 0.0f;
    for (int k = threadIdx.x; k < NPAIRS_TOTAL; k += 256) {
        F2U64 w;
        w.u = __hip_atomic_load(&slots[k], __ATOMIC_RELAXED, __HIP_MEMORY_SCOPE_AGENT);
        c += w.f.x;
        n += w.f.y;
    }
    scos[threadIdx.x] = c;
    scnt[threadIdx.x] = n;
    __syncthreads();
    for (int s = 128; s > 0; s >>= 1) {
        if (threadIdx.x < (unsigned)s) {
            scos[threadIdx.x] += scos[threadIdx.x + s];
            scnt[threadIdx.x] += scnt[threadIdx.x + s];
        }
        __syncthreads();
    }
    if (threadIdx.x == 0) out[0] = scos[0] / (1.0f + scnt[0]);
}

extern "C" void kernel_launch(void* const* d_in, const int* in_sizes, int n_in,
                              void* d_out, int out_size, void* d_ws, size_t ws_size,
                              hipStream_t stream) {
    const float* recon = (const float*)d_in[0]; // [16,17,2] f32
    const float* gt = (const float*)d_in[1];    // [16,4096,2] f32
    float* out = (float*)d_out;                 // scalar f32

    unsigned long long* slots = (unsigned long long*)d_ws;            // 2176 slots
    unsigned int* ticket = (unsigned int*)((char*)d_ws + (size_t)NPAIRS_TOTAL * 8);

    fused_kernel<<<NBLK, 256, 0, stream>>>(recon, gt, slots, ticket, out);
}

// Round 5
// 17.846 us; speedup vs baseline: 2.4192x; 2.0585x over previous
//
#include <hip/hip_runtime.h>
#include <math.h>

#define BATCH 16
#define NPTS 17
#define MPTS 4096
#define NPAIR 136                    // 17*16/2 pairs (i>j)
#define NPAIRS_TOTAL (BATCH * NPAIR) // 2176
#define NBLK (NPAIRS_TOTAL / 4)      // 544 blocks, 4 waves/block, 1 wave per pair
#define CNT 5
#define MAXDIS 1e-3f
#define EPS_ABS 1e-5f

// Kernel 1: one wave per (batch, pair). 64 lanes stripe the 4096 gt points
// (float4 = 2 points/lane/iter, 32 iters), keep 5 running mins, butterfly
// min-reduce in-wave, lane 0 plain-stores the (cos, cnt) float2 slot.
// No LDS, no atomics, no cross-block communication.
__global__ __launch_bounds__(256) void pair_kernel(const float* __restrict__ recon,
                                                   const float* __restrict__ gt,
                                                   float2* __restrict__ slots) {
    const int wv = blockIdx.x * 4 + (threadIdx.x >> 6); // pair id in [0, 2176)
    const int lane = threadIdx.x & 63;
    const int b = wv / NPAIR;
    const int p = wv - b * NPAIR;
    // decode p -> (i, j), p = i*(i-1)/2 + j, j < i  (wave-uniform scalar loop)
    int i = 1;
    while ((i * (i + 1)) / 2 <= p) ++i;
    const int j = p - (i * (i - 1)) / 2;

    const float* rp = recon + b * NPTS * 2;
    const float pix = rp[2 * i], piy = rp[2 * i + 1];
    const float pjx = rp[2 * j], pjy = rp[2 * j + 1];

    // K_c = p_i * t + p_j * (1-t), t = {0,.25,.5,.75,1}
    float m2Kx[CNT], m2Ky[CNT], k2[CNT], mn[CNT];
    #pragma unroll
    for (int c = 0; c < CNT; ++c) {
        const float t = 0.25f * (float)c;
        const float omt = 1.0f - t;
        const float Kx = pix * t + pjx * omt;
        const float Ky = piy * t + pjy * omt;
        k2[c] = Kx * Kx + Ky * Ky;
        m2Kx[c] = -2.0f * Kx;
        m2Ky[c] = -2.0f * Ky;
        mn[c] = 1e30f;
    }

    const float4* g4 = (const float4*)(gt + (size_t)b * MPTS * 2);
    #pragma unroll 4
    for (int q = lane; q < MPTS / 2; q += 64) {
        const float4 g = g4[q];
        const float g2a = g.x * g.x + g.y * g.y;
        const float g2b = g.z * g.z + g.w * g.w;
        #pragma unroll
        for (int c = 0; c < CNT; ++c) {
            // d2 = (k2 + g2) - 2*(Kx*gx + Ky*gy), fused
            const float da = fmaf(m2Kx[c], g.x, fmaf(m2Ky[c], g.y, k2[c] + g2a));
            const float db = fmaf(m2Kx[c], g.z, fmaf(m2Ky[c], g.w, k2[c] + g2b));
            mn[c] = fminf(mn[c], fminf(da, db));
        }
    }

    // in-wave butterfly min reduce
    #pragma unroll
    for (int c = 0; c < CNT; ++c) {
        #pragma unroll
        for (int off = 32; off > 0; off >>= 1)
            mn[c] = fminf(mn[c], __shfl_xor(mn[c], off, 64));
    }

    if (lane == 0) {
        const float cdis = ((((mn[0] + mn[1]) + mn[2]) + mn[3]) + mn[4]) / 5.0f;
        float cosv = 0.0f, cntv = 0.0f;
        if (cdis < MAXDIS) {
            const float u0x = rp[0], u0y = rp[1];
            const float uix = u0x - pix, uiy = u0y - piy;
            const float ujx = u0x - pjx, ujy = u0y - pjy;
            const float dot = fabsf(uix * ujx + uiy * ujy);
            const float ai = sqrtf((uix * uix + EPS_ABS) + (uiy * uiy + EPS_ABS));
            const float aj = sqrtf((ujx * ujx + EPS_ABS) + (ujy * ujy + EPS_ABS));
            cosv = dot / (ai * aj);
            cntv = 1.0f;
        }
        slots[wv] = make_float2(cosv, cntv);
    }
}

// Kernel 2: one block, deterministic fixed-order reduction of 2176 slots.
__global__ __launch_bounds__(256) void reduce_kernel(const float2* __restrict__ slots,
                                                     float* __restrict__ out) {
    __shared__ float scos[256];
    __shared__ float scnt[256];
    float c = 0.0f, n = 0.0f;
    for (int k = threadIdx.x; k < NPAIRS_TOTAL; k += 256) {
        const float2 w = slots[k];
        c += w.x;
        n += w.y;
    }
    scos[threadIdx.x] = c;
    scnt[threadIdx.x] = n;
    __syncthreads();
    for (int s = 128; s > 0; s >>= 1) {
        if (threadIdx.x < (unsigned)s) {
            scos[threadIdx.x] += scos[threadIdx.x + s];
            scnt[threadIdx.x] += scnt[threadIdx.x + s];
        }
        __syncthreads();
    }
    if (threadIdx.x == 0) out[0] = scos[0] / (1.0f + scnt[0]);
}

extern "C" void kernel_launch(void* const* d_in, const int* in_sizes, int n_in,
                              void* d_out, int out_size, void* d_ws, size_t ws_size,
                              hipStream_t stream) {
    const float* recon = (const float*)d_in[0]; // [16,17,2] f32
    const float* gt = (const float*)d_in[1];    // [16,4096,2] f32
    float* out = (float*)d_out;                 // scalar f32
    float2* slots = (float2*)d_ws;              // 2176 float2 slots

    pair_kernel<<<NBLK, 256, 0, stream>>>(recon, gt, slots);
    reduce_kernel<<<1, 256, 0, stream>>>(slots, out);
}

// Round 6
// 17.031 us; speedup vs baseline: 2.5349x; 1.0478x over previous
//
#include <hip/hip_runtime.h>
#include <math.h>

#define BATCH 16
#define NPTS 17
#define MPTS 4096
#define NPAIR 136                    // 17*16/2 pairs (i>j)
#define NPAIRS_TOTAL (BATCH * NPAIR) // 2176
#define NBLK (NPAIRS_TOTAL / 4)      // 544 blocks, 4 waves/block, 1 wave per pair
#define CNT 5
#define MAXDIS 1e-3f
#define EPS_ABS 1e-5f

// Kernel 1: one wave per (batch, pair). 64 lanes stripe the 4096 gt points
// (float4 = 2 points/lane/iter, 32 iters), keep 5 running mins, butterfly
// min-reduce in-wave. The 4 waves' (cos, cnt) results are partial-summed
// through 32 B of LDS into ONE float2 per block -> 544 slots.
__global__ __launch_bounds__(256) void pair_kernel(const float* __restrict__ recon,
                                                   const float* __restrict__ gt,
                                                   float2* __restrict__ slots) {
    const int wave = threadIdx.x >> 6;
    const int lane = threadIdx.x & 63;
    const int wv = blockIdx.x * 4 + wave;  // pair id in [0, 2176)
    const int b = wv / NPAIR;
    const int p = wv - b * NPAIR;
    // decode p -> (i, j), p = i*(i-1)/2 + j, j < i  (wave-uniform scalar loop)
    int i = 1;
    while ((i * (i + 1)) / 2 <= p) ++i;
    const int j = p - (i * (i - 1)) / 2;

    const float* rp = recon + b * NPTS * 2;
    const float pix = rp[2 * i], piy = rp[2 * i + 1];
    const float pjx = rp[2 * j], pjy = rp[2 * j + 1];

    // K_c = p_i * t + p_j * (1-t), t = {0,.25,.5,.75,1}
    float m2Kx[CNT], m2Ky[CNT], k2[CNT], mn[CNT];
    #pragma unroll
    for (int c = 0; c < CNT; ++c) {
        const float t = 0.25f * (float)c;
        const float omt = 1.0f - t;
        const float Kx = pix * t + pjx * omt;
        const float Ky = piy * t + pjy * omt;
        k2[c] = Kx * Kx + Ky * Ky;
        m2Kx[c] = -2.0f * Kx;
        m2Ky[c] = -2.0f * Ky;
        mn[c] = 1e30f;
    }

    const float4* g4 = (const float4*)(gt + (size_t)b * MPTS * 2);
    #pragma unroll 4
    for (int q = lane; q < MPTS / 2; q += 64) {
        const float4 g = g4[q];
        const float g2a = g.x * g.x + g.y * g.y;
        const float g2b = g.z * g.z + g.w * g.w;
        #pragma unroll
        for (int c = 0; c < CNT; ++c) {
            // d2 = (k2 + g2) - 2*(Kx*gx + Ky*gy), fused
            const float da = fmaf(m2Kx[c], g.x, fmaf(m2Ky[c], g.y, k2[c] + g2a));
            const float db = fmaf(m2Kx[c], g.z, fmaf(m2Ky[c], g.w, k2[c] + g2b));
            mn[c] = fminf(mn[c], fminf(da, db));
        }
    }

    // in-wave butterfly min reduce
    #pragma unroll
    for (int c = 0; c < CNT; ++c) {
        #pragma unroll
        for (int off = 32; off > 0; off >>= 1)
            mn[c] = fminf(mn[c], __shfl_xor(mn[c], off, 64));
    }

    __shared__ float2 part[4];
    if (lane == 0) {
        const float cdis = ((((mn[0] + mn[1]) + mn[2]) + mn[3]) + mn[4]) / 5.0f;
        float cosv = 0.0f, cntv = 0.0f;
        if (cdis < MAXDIS) {
            const float u0x = rp[0], u0y = rp[1];
            const float uix = u0x - pix, uiy = u0y - piy;
            const float ujx = u0x - pjx, ujy = u0y - pjy;
            const float dot = fabsf(uix * ujx + uiy * ujy);
            const float ai = sqrtf((uix * uix + EPS_ABS) + (uiy * uiy + EPS_ABS));
            const float aj = sqrtf((ujx * ujx + EPS_ABS) + (ujy * ujy + EPS_ABS));
            cosv = dot / (ai * aj);
            cntv = 1.0f;
        }
        part[wave] = make_float2(cosv, cntv);
    }
    __syncthreads();
    if (threadIdx.x == 0) {
        // fixed-order partial sum of the block's 4 pairs
        const float2 a = part[0], bb = part[1], cc = part[2], dd = part[3];
        slots[blockIdx.x] = make_float2(((a.x + bb.x) + cc.x) + dd.x,
                                        ((a.y + bb.y) + cc.y) + dd.y);
    }
}

// Kernel 2: ONE WAVE. 64 lanes stride the 544 block-partials (<=9 each,
// fixed order), butterfly shuffle sum, lane 0 writes the scalar.
__global__ __launch_bounds__(64) void reduce_kernel(const float2* __restrict__ slots,
                                                    float* __restrict__ out) {
    const int lane = threadIdx.x;
    float c = 0.0f, n = 0.0f;
    #pragma unroll
    for (int m = 0; m < 9; ++m) {
        const int k = lane + 64 * m;
        if (k < NBLK) {
            const float2 w = slots[k];
            c += w.x;
            n += w.y;
        }
    }
    #pragma unroll
    for (int off = 32; off > 0; off >>= 1) {
        c += __shfl_xor(c, off, 64);
        n += __shfl_xor(n, off, 64);
    }
    if (lane == 0) out[0] = c / (1.0f + n);
}

extern "C" void kernel_launch(void* const* d_in, const int* in_sizes, int n_in,
                              void* d_out, int out_size, void* d_ws, size_t ws_size,
                              hipStream_t stream) {
    const float* recon = (const float*)d_in[0]; // [16,17,2] f32
    const float* gt = (const float*)d_in[1];    // [16,4096,2] f32
    float* out = (float*)d_out;                 // scalar f32
    float2* slots = (float2*)d_ws;              // 544 float2 block partials

    pair_kernel<<<NBLK, 256, 0, stream>>>(recon, gt, slots);
    reduce_kernel<<<1, 64, 0, stream>>>(slots, out);
}

// Round 7
// 15.311 us; speedup vs baseline: 2.8197x; 1.1123x over previous
//
#include <hip/hip_runtime.h>
#include <math.h>

#define BATCH 16
#define NPTS 17
#define MPTS 4096
#define NPAIR 136                    // 17*16/2 pairs (i>j)
#define NPAIRS_TOTAL (BATCH * NPAIR) // 2176
#define NBLK (NPAIRS_TOTAL / 4)      // 544 blocks, 4 waves/block, 1 wave per pair
#define CNT 5
#define MAXDIS 1e-3f
#define EPS_ABS 1e-5f

// Kernel 1: one wave per (batch, pair). Quadratic form of the segment-sample
// distance: K(t) = p_j + t*e, e = p_i - p_j, so
//   d2(t) = ||p_j - g||^2 + t * (2 e.(p_j - g)) + t^2 ||e||^2  =  A + t*B + t^2*E.
// t^2*E is wave-uniform per sample c, so we min the SHIFTED value A + t_c*B
// over g and add t_c^2*E back after the reduce. Inner loop: per point
// {sub,sub,mul,fma, mul,fma} + per-c {fma,min} (c=0: min only; c=4: add,min).
__global__ __launch_bounds__(256) void pair_kernel(const float* __restrict__ recon,
                                                   const float* __restrict__ gt,
                                                   float2* __restrict__ slots) {
    const int wave = threadIdx.x >> 6;
    const int lane = threadIdx.x & 63;
    const int wv = blockIdx.x * 4 + wave;  // pair id in [0, 2176)
    const int b = wv / NPAIR;
    const int p = wv - b * NPAIR;
    // decode p -> (i, j), p = i*(i-1)/2 + j, j < i  (wave-uniform scalar loop)
    int i = 1;
    while ((i * (i + 1)) / 2 <= p) ++i;
    const int j = p - (i * (i - 1)) / 2;

    const float* rp = recon + b * NPTS * 2;
    const float pix = rp[2 * i], piy = rp[2 * i + 1];
    const float pjx = rp[2 * j], pjy = rp[2 * j + 1];

    const float ex = pix - pjx, ey = piy - pjy;
    const float e2x = 2.0f * ex, e2y = 2.0f * ey;
    const float E = ex * ex + ey * ey;

    float ms0 = 1e30f, ms1 = 1e30f, ms2 = 1e30f, ms3 = 1e30f, ms4 = 1e30f;

    const float4* g4 = (const float4*)(gt + (size_t)b * MPTS * 2);
    #pragma unroll 4
    for (int q = lane; q < MPTS / 2; q += 64) {
        const float4 g = g4[q];
        // point a
        const float dxa = pjx - g.x, dya = pjy - g.y;
        const float Aa = fmaf(dxa, dxa, dya * dya);
        const float Ba = fmaf(e2x, dxa, e2y * dya);
        // point b
        const float dxb = pjx - g.z, dyb = pjy - g.w;
        const float Ab = fmaf(dxb, dxb, dyb * dyb);
        const float Bb = fmaf(e2x, dxb, e2y * dyb);

        ms0 = fminf(ms0, fminf(Aa, Ab));
        ms1 = fminf(ms1, fminf(fmaf(0.25f, Ba, Aa), fmaf(0.25f, Bb, Ab)));
        ms2 = fminf(ms2, fminf(fmaf(0.50f, Ba, Aa), fmaf(0.50f, Bb, Ab)));
        ms3 = fminf(ms3, fminf(fmaf(0.75f, Ba, Aa), fmaf(0.75f, Bb, Ab)));
        ms4 = fminf(ms4, fminf(Aa + Ba, Ab + Bb));
    }

    // in-wave butterfly min reduce of the 5 shifted mins
    #pragma unroll
    for (int off = 32; off > 0; off >>= 1) {
        ms0 = fminf(ms0, __shfl_xor(ms0, off, 64));
        ms1 = fminf(ms1, __shfl_xor(ms1, off, 64));
        ms2 = fminf(ms2, __shfl_xor(ms2, off, 64));
        ms3 = fminf(ms3, __shfl_xor(ms3, off, 64));
        ms4 = fminf(ms4, __shfl_xor(ms4, off, 64));
    }

    __shared__ float2 part[4];
    if (lane == 0) {
        // un-shift: mn[c] = ms[c] + t_c^2 * E; mean over the 5 samples.
        const float m0 = ms0;
        const float m1 = fmaf(0.0625f, E, ms1);
        const float m2 = fmaf(0.25f, E, ms2);
        const float m3 = fmaf(0.5625f, E, ms3);
        const float m4 = ms4 + E;
        const float cdis = ((((m0 + m1) + m2) + m3) + m4) / 5.0f;
        float cosv = 0.0f, cntv = 0.0f;
        if (cdis < MAXDIS) {
            const float u0x = rp[0], u0y = rp[1];
            const float uix = u0x - pix, uiy = u0y - piy;
            const float ujx = u0x - pjx, ujy = u0y - pjy;
            const float dot = fabsf(uix * ujx + uiy * ujy);
            const float ai = sqrtf((uix * uix + EPS_ABS) + (uiy * uiy + EPS_ABS));
            const float aj = sqrtf((ujx * ujx + EPS_ABS) + (ujy * ujy + EPS_ABS));
            cosv = dot / (ai * aj);
            cntv = 1.0f;
        }
        part[wave] = make_float2(cosv, cntv);
    }
    __syncthreads();
    if (threadIdx.x == 0) {
        // fixed-order partial sum of the block's 4 pairs
        const float2 a = part[0], bb = part[1], cc = part[2], dd = part[3];
        slots[blockIdx.x] = make_float2(((a.x + bb.x) + cc.x) + dd.x,
                                        ((a.y + bb.y) + cc.y) + dd.y);
    }
}

// Kernel 2: ONE WAVE. 64 lanes stride the 544 block-partials (<=9 each,
// fixed order), butterfly shuffle sum, lane 0 writes the scalar.
__global__ __launch_bounds__(64) void reduce_kernel(const float2* __restrict__ slots,
                                                    float* __restrict__ out) {
    const int lane = threadIdx.x;
    float c = 0.0f, n = 0.0f;
    #pragma unroll
    for (int m = 0; m < 9; ++m) {
        const int k = lane + 64 * m;
        if (k < NBLK) {
            const float2 w = slots[k];
            c += w.x;
            n += w.y;
        }
    }
    #pragma unroll
    for (int off = 32; off > 0; off >>= 1) {
        c += __shfl_xor(c, off, 64);
        n += __shfl_xor(n, off, 64);
    }
    if (lane == 0) out[0] = c / (1.0f + n);
}

extern "C" void kernel_launch(void* const* d_in, const int* in_sizes, int n_in,
                              void* d_out, int out_size, void* d_ws, size_t ws_size,
                              hipStream_t stream) {
    const float* recon = (const float*)d_in[0]; // [16,17,2] f32
    const float* gt = (const float*)d_in[1];    // [16,4096,2] f32
    float* out = (float*)d_out;                 // scalar f32
    float2* slots = (float2*)d_ws;              // 544 float2 block partials

    pair_kernel<<<NBLK, 256, 0, stream>>>(recon, gt, slots);
    reduce_kernel<<<1, 64, 0, stream>>>(slots, out);
}

// Round 8
// 13.147 us; speedup vs baseline: 3.2838x; 1.1646x over previous
//
#include <hip/hip_runtime.h>
#include <math.h>

#define BATCH 16
#define NPTS 17
#define MPTS 4096
#define NPAIR 136                    // 17*16/2 pairs (i>j)
#define NPAIRS_TOTAL (BATCH * NPAIR) // 2176
#define CNT 5
#define MAXDIS 1e-3f
#define EPS_ABS 1e-5f

// Kernel 1: ONE BLOCK PER PAIR (2176 blocks, 256 threads). The 4 waves each
// scan a quarter of the 4096 gt points (8 fully-unrolled float4 iters/lane),
// tracking the 5 shifted mins ms_c = min_g(A + t_c*B) of the quadratic form
//   d2(t) = A + t*B + t^2*E,  A=||p_j-g||^2, B=2e.(p_j-g), E=||e||^2.
// Butterfly per wave -> 4x5 LDS min-combine -> thread 0 un-shifts (+t_c^2*E),
// means, thresholds, computes the cos term, writes one float2 slot.
// Wave-granularity work is T/4, so the busiest SIMD does 2.25 rounds instead
// of 3 (8704 quarter-waves over 1024 SIMDs) -- cuts the balance tail.
__global__ __launch_bounds__(256) void pair_kernel(const float* __restrict__ recon,
                                                   const float* __restrict__ gt,
                                                   float2* __restrict__ slots) {
    const int blk = blockIdx.x;      // pair id in [0, 2176)
    const int wave = threadIdx.x >> 6;
    const int lane = threadIdx.x & 63;
    const int b = blk / NPAIR;
    const int p = blk - b * NPAIR;
    // decode p -> (i, j), p = i*(i-1)/2 + j, j < i  (block-uniform scalar loop)
    int i = 1;
    while ((i * (i + 1)) / 2 <= p) ++i;
    const int j = p - (i * (i - 1)) / 2;

    const float* rp = recon + b * NPTS * 2;
    const float pix = rp[2 * i], piy = rp[2 * i + 1];
    const float pjx = rp[2 * j], pjy = rp[2 * j + 1];

    const float ex = pix - pjx, ey = piy - pjy;
    const float e2x = 2.0f * ex, e2y = 2.0f * ey;
    const float E = ex * ex + ey * ey;

    float ms0 = 1e30f, ms1 = 1e30f, ms2 = 1e30f, ms3 = 1e30f, ms4 = 1e30f;

    const float4* g4 = (const float4*)(gt + (size_t)b * MPTS * 2);
    #pragma unroll
    for (int it = 0; it < 8; ++it) {
        const float4 g = g4[threadIdx.x + (it << 8)];
        // point a
        const float dxa = pjx - g.x, dya = pjy - g.y;
        const float Aa = fmaf(dxa, dxa, dya * dya);
        const float Ba = fmaf(e2x, dxa, e2y * dya);
        // point b
        const float dxb = pjx - g.z, dyb = pjy - g.w;
        const float Ab = fmaf(dxb, dxb, dyb * dyb);
        const float Bb = fmaf(e2x, dxb, e2y * dyb);

        ms0 = fminf(ms0, fminf(Aa, Ab));
        ms1 = fminf(ms1, fminf(fmaf(0.25f, Ba, Aa), fmaf(0.25f, Bb, Ab)));
        ms2 = fminf(ms2, fminf(fmaf(0.50f, Ba, Aa), fmaf(0.50f, Bb, Ab)));
        ms3 = fminf(ms3, fminf(fmaf(0.75f, Ba, Aa), fmaf(0.75f, Bb, Ab)));
        ms4 = fminf(ms4, fminf(Aa + Ba, Ab + Bb));
    }

    // in-wave butterfly min reduce
    #pragma unroll
    for (int off = 32; off > 0; off >>= 1) {
        ms0 = fminf(ms0, __shfl_xor(ms0, off, 64));
        ms1 = fminf(ms1, __shfl_xor(ms1, off, 64));
        ms2 = fminf(ms2, __shfl_xor(ms2, off, 64));
        ms3 = fminf(ms3, __shfl_xor(ms3, off, 64));
        ms4 = fminf(ms4, __shfl_xor(ms4, off, 64));
    }

    __shared__ float part[4][CNT];
    if (lane == 0) {
        part[wave][0] = ms0;
        part[wave][1] = ms1;
        part[wave][2] = ms2;
        part[wave][3] = ms3;
        part[wave][4] = ms4;
    }
    __syncthreads();

    if (threadIdx.x == 0) {
        float m[CNT];
        #pragma unroll
        for (int c = 0; c < CNT; ++c)
            m[c] = fminf(fminf(part[0][c], part[1][c]),
                         fminf(part[2][c], part[3][c]));
        // un-shift: mn[c] = ms[c] + t_c^2 * E; mean over the 5 samples
        const float m0 = m[0];
        const float m1 = fmaf(0.0625f, E, m[1]);
        const float m2 = fmaf(0.25f, E, m[2]);
        const float m3 = fmaf(0.5625f, E, m[3]);
        const float m4 = m[4] + E;
        const float cdis = ((((m0 + m1) + m2) + m3) + m4) / 5.0f;

        float cosv = 0.0f, cntv = 0.0f;
        if (cdis < MAXDIS) {
            const float u0x = rp[0], u0y = rp[1];
            const float uix = u0x - pix, uiy = u0y - piy;
            const float ujx = u0x - pjx, ujy = u0y - pjy;
            const float dot = fabsf(uix * ujx + uiy * ujy);
            const float ai = sqrtf((uix * uix + EPS_ABS) + (uiy * uiy + EPS_ABS));
            const float aj = sqrtf((ujx * ujx + EPS_ABS) + (ujy * ujy + EPS_ABS));
            cosv = dot / (ai * aj);
            cntv = 1.0f;
        }
        slots[blk] = make_float2(cosv, cntv);
    }
}

// Kernel 2: ONE WAVE. 64 lanes stride the 2176 pair slots (34 exact iters,
// fixed order), butterfly shuffle sum, lane 0 writes the scalar.
__global__ __launch_bounds__(64) void reduce_kernel(const float2* __restrict__ slots,
                                                    float* __restrict__ out) {
    const int lane = threadIdx.x;
    float c = 0.0f, n = 0.0f;
    #pragma unroll
    for (int m = 0; m < NPAIRS_TOTAL / 64; ++m) {
        const float2 w = slots[lane + 64 * m];
        c += w.x;
        n += w.y;
    }
    #pragma unroll
    for (int off = 32; off > 0; off >>= 1) {
        c += __shfl_xor(c, off, 64);
        n += __shfl_xor(n, off, 64);
    }
    if (lane == 0) out[0] = c / (1.0f + n);
}

extern "C" void kernel_launch(void* const* d_in, const int* in_sizes, int n_in,
                              void* d_out, int out_size, void* d_ws, size_t ws_size,
                              hipStream_t stream) {
    const float* recon = (const float*)d_in[0]; // [16,17,2] f32
    const float* gt = (const float*)d_in[1];    // [16,4096,2] f32
    float* out = (float*)d_out;                 // scalar f32
    float2* slots = (float2*)d_ws;              // 2176 float2 pair slots

    pair_kernel<<<NPAIRS_TOTAL, 256, 0, stream>>>(recon, gt, slots);
    reduce_kernel<<<1, 64, 0, stream>>>(slots, out);
}